// Round 3
// baseline (789.203 us; speedup 1.0000x reference)
//
#include <hip/hip_runtime.h>

// FUSE hydrological model: T=8192 steps, H=4096 chains.
// Parallel-in-time: C=16 chunks of L=512; chunk c>=1 re-simulates the
// preceding L steps as warm-up (contraction ~e^-12..e^-31 kills the splice
// error) then emits its L outputs. This round: 2 chains per thread.
//  - per step a thread reads 24 contiguous bytes (3x dwordx2) covering both
//    chains' (p,pet): halves load count, doubles wave burst to 1536 B,
//    halves stream count -> better DRAM efficiency (the current limiter).
//  - one dwordx2 nontemporal store per step for both runoffs.
//  - two independent log/exp dependency chains interleave for free ILP.

constexpr int T = 8192;
constexpr int H = 4096;
constexpr int C = 16;          // time chunks
constexpr int L = T / C;       // 512 steps out per chunk; warm-up = L
constexpr float EPS = 1e-6f;
constexpr int U = 8;           // prefetch depth (steps)

typedef float f32x2 __attribute__((ext_vector_type(2)));
typedef float f32x4 __attribute__((ext_vector_type(4)));

__device__ __forceinline__ float hw_log2(float x) { return __builtin_amdgcn_logf(x); }
__device__ __forceinline__ float hw_exp2(float x) { return __builtin_amdgcn_exp2f(x); }
__device__ __forceinline__ float med3(float x, float lo, float hi) {
    return __builtin_amdgcn_fmed3f(x, lo, hi);
}

struct Chain {
    float m1, m2, percrte, baserte, qpow, bexp, inv_m1, inv_m2, s1, s2;
};

__device__ __forceinline__ void init_chain(Chain& ch, const f32x4 q0, const f32x4 q1,
                                           int half,   // 0: params in q0 + q1.xy, 1: q1.zw... see below
                                           const float* lo, const float* hi) {
    // caller passes the 6 raws explicitly instead; keep simple
}

__device__ __forceinline__ float fuse_step(Chain& ch, float p, float pet) {
    float r1 = __builtin_fmaxf(ch.s1 * ch.inv_m1, EPS);
    float r2 = __builtin_fmaxf(ch.s2 * ch.inv_m2, EPS);
    float pw1 = hw_exp2(ch.bexp * hw_log2(r1));   // r1^axv_bexp
    float pw2 = hw_exp2(ch.qpow * hw_log2(r2));   // r2^qb_powr
    float qsx = pw1 * p;
    float a = ch.s1 + p;
    a = __builtin_fmaf(-pet, r1, a);              // - e1
    a = __builtin_fmaf(-ch.percrte, r1, a);       // - q12
    ch.s1 = med3(a - qsx, 0.0f, ch.m1);
    float b = __builtin_fmaf(ch.percrte, r1, ch.s2);
    ch.s2 = med3(__builtin_fmaf(-ch.baserte, pw2, b), 0.0f, ch.m2);
    return __builtin_fmaf(ch.baserte, pw2, qsx);  // runoff (DT=1)
}

__global__ __launch_bounds__(64, 1)
void fuse_scan_kernel(const float* __restrict__ forcing,
                      const float* __restrict__ initial_state,
                      const float* __restrict__ raw_params,
                      const float* __restrict__ lo,
                      const float* __restrict__ hi,
                      float* __restrict__ out)
{
    const int i = blockIdx.x * 64 + threadIdx.x;   // 0..H/2-1: chains 2i, 2i+1
    const int c = blockIdx.y;                      // time-chunk id

    // --- parameters for both chains: 12 floats, 48i bytes -> 16-aligned ---
    constexpr float LOG2E = 1.4426950408889634f;
    const f32x4* rp4 = (const f32x4*)(raw_params + 12 * i);
    f32x4 q0 = rp4[0], q1 = rp4[1], q2 = rp4[2];
    float raw[12] = { q0.x, q0.y, q0.z, q0.w, q1.x, q1.y,
                      q1.z, q1.w, q2.x, q2.y, q2.z, q2.w };
    float ph[12];
#pragma unroll
    for (int j = 0; j < 12; ++j) {
        float s = 1.0f / (1.0f + hw_exp2(-raw[j] * LOG2E));
        ph[j] = lo[j % 6] + (hi[j % 6] - lo[j % 6]) * s;
    }
    Chain ch0, ch1;
    ch0.m1 = ph[0];  ch0.m2 = ph[1];  ch0.percrte = ph[2];
    ch0.baserte = ph[3]; ch0.qpow = ph[4]; ch0.bexp = ph[5];
    ch1.m1 = ph[6];  ch1.m2 = ph[7];  ch1.percrte = ph[8];
    ch1.baserte = ph[9]; ch1.qpow = ph[10]; ch1.bexp = ph[11];
    ch0.inv_m1 = 1.0f / ch0.m1;  ch0.inv_m2 = 1.0f / ch0.m2;
    ch1.inv_m1 = 1.0f / ch1.m1;  ch1.inv_m2 = 1.0f / ch1.m2;

    // --- initial states: 4 floats at byte 16i -> 16-aligned ---
    const f32x4 st = *(const f32x4*)(initial_state + 4 * i);
    ch0.s1 = st.x; ch0.s2 = st.y; ch1.s1 = st.z; ch1.s2 = st.w;

    const int t0 = (c == 0) ? 0 : (c - 1) * L;     // first simulated step

    // 32-bit byte offsets against SGPR bases (max ~400 MB < 4 GB)
    const char* __restrict__ fbase = (const char*)forcing;
    char* __restrict__ obase = (char*)out;
    constexpr unsigned FSTEP = (unsigned)H * 3u * 4u;   // 49152 B / timestep
    constexpr unsigned OSTEP = (unsigned)H * 4u;        // 16384 B / timestep
    unsigned foff = (unsigned)t0 * FSTEP + (unsigned)i * 24u;
    unsigned ooff = (unsigned)(c * L) * OSTEP + (unsigned)i * 8u;

    // rotating prefetch buffers: (p,pet) x 2 chains x U steps, registers
    float p0b[U], e0b[U], p1b[U], e1b[U];
#define PREFETCH(k)                                                    \
    do {                                                               \
        f32x2 A = *(const f32x2*)(fbase + foff);        /* p0,pet0 */  \
        f32x2 B = *(const f32x2*)(fbase + foff + 8);    /* x0,p1  */   \
        f32x2 Cv = *(const f32x2*)(fbase + foff + 16);  /* pet1,x1 */  \
        p0b[k] = A.x; e0b[k] = A.y; p1b[k] = B.y; e1b[k] = Cv.x;       \
        foff += FSTEP;                                                 \
    } while (0)

#pragma unroll
    for (int k = 0; k < U; ++k) PREFETCH(k);

    // --- warm-up: L steps, no stores (block-uniform branch) ---
    if (c != 0) {
        for (int t = 0; t < L; t += U) {
#pragma unroll
            for (int k = 0; k < U; ++k) {
                const float p0 = p0b[k], e0 = e0b[k];
                const float p1 = p1b[k], e1 = e1b[k];
                PREFETCH(k);
                (void)fuse_step(ch0, p0, e0);
                (void)fuse_step(ch1, p1, e1);
            }
        }
    }

    // --- output: L-U steps with prefetch ---
    for (int t = 0; t < L - U; t += U) {
#pragma unroll
        for (int k = 0; k < U; ++k) {
            const float p0 = p0b[k], e0 = e0b[k];
            const float p1 = p1b[k], e1 = e1b[k];
            PREFETCH(k);
            f32x2 r;
            r.x = fuse_step(ch0, p0, e0);
            r.y = fuse_step(ch1, p1, e1);
            __builtin_nontemporal_store(r, (f32x2*)(obase + ooff));
            ooff += OSTEP;
        }
    }
    // --- epilogue: last U steps, no prefetch ---
#pragma unroll
    for (int k = 0; k < U; ++k) {
        f32x2 r;
        r.x = fuse_step(ch0, p0b[k], e0b[k]);
        r.y = fuse_step(ch1, p1b[k], e1b[k]);
        __builtin_nontemporal_store(r, (f32x2*)(obase + ooff));
        ooff += OSTEP;
    }
#undef PREFETCH
}

extern "C" void kernel_launch(void* const* d_in, const int* in_sizes, int n_in,
                              void* d_out, int out_size, void* d_ws, size_t ws_size,
                              hipStream_t stream) {
    const float* forcing       = (const float*)d_in[0];  // (T, H, 3)
    const float* initial_state = (const float*)d_in[1];  // (H, 2)
    const float* raw_params    = (const float*)d_in[2];  // (H, 6)
    const float* param_lower   = (const float*)d_in[3];  // (6,)
    const float* param_upper   = (const float*)d_in[4];  // (6,)
    float* out = (float*)d_out;                          // (T, H)

    fuse_scan_kernel<<<dim3((H / 2) / 64, C), dim3(64), 0, stream>>>(
        forcing, initial_state, raw_params, param_lower, param_upper, out);
}

// Round 4
// 766.689 us; speedup vs baseline: 1.0294x; 1.0294x over previous
//
#include <hip/hip_runtime.h>

// FUSE hydrological model: T=8192 steps, H=4096 chains.
// Parallel-in-time: C=16 chunks of L=512; chunk c>=1 re-simulates the
// preceding L steps as warm-up (contraction kills the splice error), then
// emits its L outputs. 2 chains per thread: each step reads 24 contiguous
// bytes (3x dwordx2) per lane -> 1536 B per wave-step burst, 512 streams.
// R4 fix vs R3: prefetch depth U restored to 16. R3's U=8 put in-flight
// bytes (5.9 MB) right at the BW*latency product (~5.8 MB) -> latency
// cliff, 1.35 TB/s. U=16 gives 12.6 MB in flight (2.2x margin), matching
// R2's proven latency coverage while keeping the doubled burst size.

constexpr int T = 8192;
constexpr int H = 4096;
constexpr int C = 16;          // time chunks
constexpr int L = T / C;       // 512 steps out per chunk; warm-up = L
constexpr float EPS = 1e-6f;
constexpr int U = 16;          // prefetch depth (steps)

typedef float f32x2 __attribute__((ext_vector_type(2)));
typedef float f32x4 __attribute__((ext_vector_type(4)));

__device__ __forceinline__ float hw_log2(float x) { return __builtin_amdgcn_logf(x); }
__device__ __forceinline__ float hw_exp2(float x) { return __builtin_amdgcn_exp2f(x); }
__device__ __forceinline__ float med3(float x, float lo, float hi) {
    return __builtin_amdgcn_fmed3f(x, lo, hi);
}

struct Chain {
    float m1, m2, percrte, baserte, qpow, bexp, inv_m1, inv_m2, s1, s2;
};

__device__ __forceinline__ float fuse_step(Chain& ch, float p, float pet) {
    float r1 = __builtin_fmaxf(ch.s1 * ch.inv_m1, EPS);
    float r2 = __builtin_fmaxf(ch.s2 * ch.inv_m2, EPS);
    float pw1 = hw_exp2(ch.bexp * hw_log2(r1));   // r1^axv_bexp
    float pw2 = hw_exp2(ch.qpow * hw_log2(r2));   // r2^qb_powr
    float qsx = pw1 * p;
    float a = ch.s1 + p;
    a = __builtin_fmaf(-pet, r1, a);              // - e1
    a = __builtin_fmaf(-ch.percrte, r1, a);       // - q12
    ch.s1 = med3(a - qsx, 0.0f, ch.m1);
    float b = __builtin_fmaf(ch.percrte, r1, ch.s2);
    ch.s2 = med3(__builtin_fmaf(-ch.baserte, pw2, b), 0.0f, ch.m2);
    return __builtin_fmaf(ch.baserte, pw2, qsx);  // runoff (DT=1)
}

__global__ __launch_bounds__(64, 1)
void fuse_scan_kernel(const float* __restrict__ forcing,
                      const float* __restrict__ initial_state,
                      const float* __restrict__ raw_params,
                      const float* __restrict__ lo,
                      const float* __restrict__ hi,
                      float* __restrict__ out)
{
    const int i = blockIdx.x * 64 + threadIdx.x;   // 0..H/2-1: chains 2i, 2i+1
    const int c = blockIdx.y;                      // time-chunk id

    // --- parameters for both chains: 12 floats, 48i bytes -> 16-aligned ---
    constexpr float LOG2E = 1.4426950408889634f;
    const f32x4* rp4 = (const f32x4*)(raw_params + 12 * i);
    f32x4 q0 = rp4[0], q1 = rp4[1], q2 = rp4[2];
    float raw[12] = { q0.x, q0.y, q0.z, q0.w, q1.x, q1.y,
                      q1.z, q1.w, q2.x, q2.y, q2.z, q2.w };
    float ph[12];
#pragma unroll
    for (int j = 0; j < 12; ++j) {
        float s = 1.0f / (1.0f + hw_exp2(-raw[j] * LOG2E));
        ph[j] = lo[j % 6] + (hi[j % 6] - lo[j % 6]) * s;
    }
    Chain ch0, ch1;
    ch0.m1 = ph[0];  ch0.m2 = ph[1];  ch0.percrte = ph[2];
    ch0.baserte = ph[3]; ch0.qpow = ph[4]; ch0.bexp = ph[5];
    ch1.m1 = ph[6];  ch1.m2 = ph[7];  ch1.percrte = ph[8];
    ch1.baserte = ph[9]; ch1.qpow = ph[10]; ch1.bexp = ph[11];
    ch0.inv_m1 = 1.0f / ch0.m1;  ch0.inv_m2 = 1.0f / ch0.m2;
    ch1.inv_m1 = 1.0f / ch1.m1;  ch1.inv_m2 = 1.0f / ch1.m2;

    // --- initial states: 4 floats at byte 16i -> 16-aligned ---
    const f32x4 st = *(const f32x4*)(initial_state + 4 * i);
    ch0.s1 = st.x; ch0.s2 = st.y; ch1.s1 = st.z; ch1.s2 = st.w;

    const int t0 = (c == 0) ? 0 : (c - 1) * L;     // first simulated step

    // 32-bit byte offsets against SGPR bases (max ~400 MB < 4 GB)
    const char* __restrict__ fbase = (const char*)forcing;
    char* __restrict__ obase = (char*)out;
    constexpr unsigned FSTEP = (unsigned)H * 3u * 4u;   // 49152 B / timestep
    constexpr unsigned OSTEP = (unsigned)H * 4u;        // 16384 B / timestep
    unsigned foff = (unsigned)t0 * FSTEP + (unsigned)i * 24u;
    unsigned ooff = (unsigned)(c * L) * OSTEP + (unsigned)i * 8u;

    // rotating prefetch buffers: (p,pet) x 2 chains x U steps, registers
    float p0b[U], e0b[U], p1b[U], e1b[U];
#define PREFETCH(k)                                                    \
    do {                                                               \
        f32x2 A = *(const f32x2*)(fbase + foff);        /* p0,pet0 */  \
        f32x2 B = *(const f32x2*)(fbase + foff + 8);    /* x0,p1  */   \
        f32x2 Cv = *(const f32x2*)(fbase + foff + 16);  /* pet1,x1 */  \
        p0b[k] = A.x; e0b[k] = A.y; p1b[k] = B.y; e1b[k] = Cv.x;       \
        foff += FSTEP;                                                 \
    } while (0)

#pragma unroll
    for (int k = 0; k < U; ++k) PREFETCH(k);

    // --- warm-up: L steps, no stores (block-uniform branch) ---
    if (c != 0) {
        for (int t = 0; t < L; t += U) {
#pragma unroll
            for (int k = 0; k < U; ++k) {
                const float p0 = p0b[k], e0 = e0b[k];
                const float p1 = p1b[k], e1 = e1b[k];
                PREFETCH(k);
                (void)fuse_step(ch0, p0, e0);
                (void)fuse_step(ch1, p1, e1);
            }
        }
    }

    // --- output: L-U steps with prefetch ---
    for (int t = 0; t < L - U; t += U) {
#pragma unroll
        for (int k = 0; k < U; ++k) {
            const float p0 = p0b[k], e0 = e0b[k];
            const float p1 = p1b[k], e1 = e1b[k];
            PREFETCH(k);
            f32x2 r;
            r.x = fuse_step(ch0, p0, e0);
            r.y = fuse_step(ch1, p1, e1);
            __builtin_nontemporal_store(r, (f32x2*)(obase + ooff));
            ooff += OSTEP;
        }
    }
    // --- epilogue: last U steps, no prefetch ---
#pragma unroll
    for (int k = 0; k < U; ++k) {
        f32x2 r;
        r.x = fuse_step(ch0, p0b[k], e0b[k]);
        r.y = fuse_step(ch1, p1b[k], e1b[k]);
        __builtin_nontemporal_store(r, (f32x2*)(obase + ooff));
        ooff += OSTEP;
    }
#undef PREFETCH
}

extern "C" void kernel_launch(void* const* d_in, const int* in_sizes, int n_in,
                              void* d_out, int out_size, void* d_ws, size_t ws_size,
                              hipStream_t stream) {
    const float* forcing       = (const float*)d_in[0];  // (T, H, 3)
    const float* initial_state = (const float*)d_in[1];  // (H, 2)
    const float* raw_params    = (const float*)d_in[2];  // (H, 6)
    const float* param_lower   = (const float*)d_in[3];  // (6,)
    const float* param_upper   = (const float*)d_in[4];  // (6,)
    float* out = (float*)d_out;                          // (T, H)

    fuse_scan_kernel<<<dim3((H / 2) / 64, C), dim3(64), 0, stream>>>(
        forcing, initial_state, raw_params, param_lower, param_upper, out);
}